// Round 11
// baseline (180.965 us; speedup 1.0000x reference)
//
#include <hip/hip_runtime.h>
#include <math.h>

#define F 128
#define NTOT 2080
#define CN 2048
#define AN 16
#define NA 17   // max agents (step>0)
#define CHK 128 // cities per chunk (k35/k6)
#define NCHK 16 // CN/CHK

__device__ __forceinline__ float wmax(float v){
  #pragma unroll
  for(int m=32;m;m>>=1) v = fmaxf(v, __shfl_xor(v, m, 64));
  return v;
}
__device__ __forceinline__ float wsum(float v){
  #pragma unroll
  for(int m=32;m;m>>=1) v += __shfl_xor(v, m, 64);
  return v;
}

// K0t: tiled transposes of Wg(128x512), Wc(384x256), Wp(128x128), Wa(128x384)
__global__ __launch_bounds__(256) void k0t_transpose(
      const float* __restrict__ Wg, const float* __restrict__ Wc,
      const float* __restrict__ Wp, const float* __restrict__ Wa,
      float* __restrict__ WgT, float* __restrict__ WcT,
      float* __restrict__ WpT, float* __restrict__ WaT){
  __shared__ float tile[32][33];
  const int z = blockIdx.z;
  const float* src; float* dst; int R, C;
  if(z==0){ src=Wg; dst=WgT; R=128; C=512; }
  else if(z==1){ src=Wc; dst=WcT; R=384; C=256; }
  else if(z==2){ src=Wp; dst=WpT; R=128; C=128; }
  else { src=Wa; dst=WaT; R=128; C=384; }
  const int c0 = blockIdx.x*32, r0 = blockIdx.y*32;
  if(c0>=C || r0>=R) return;
  const int tx = threadIdx.x&31, ty = threadIdx.x>>5;   // 32x8
  #pragma unroll
  for(int rr=0;rr<4;rr++)
    tile[ty+rr*8][tx] = src[(size_t)(r0+ty+rr*8)*C + c0 + tx];
  __syncthreads();
  #pragma unroll
  for(int rr=0;rr<4;rr++)
    dst[(size_t)(c0+ty+rr*8)*R + r0 + tx] = tile[tx][ty+rr*8];
}

// K0a: Wpy = Wp @ Wcy2
__global__ __launch_bounds__(128) void k0a_wpy(const float* __restrict__ Wp, const float* __restrict__ Wc,
                                               float* __restrict__ Wpy){
  const int k = blockIdx.x, i = threadIdx.x;
  float acc = 0.f;
  const float* wp = Wp + (size_t)k*F;
  for(int j=0;j<F;j++) acc += wp[j]*Wc[(size_t)(128+j)*256 + 128 + i];
  Wpy[k*F+i] = acc;
}

// K0b: M1 = Wcz2^T @ Wpy
__global__ __launch_bounds__(128) void k0b_m1(const float* __restrict__ Wc, const float* __restrict__ Wpy,
                                              float* __restrict__ M1){
  const int jc = blockIdx.x, i = threadIdx.x;
  float acc = 0.f;
  for(int k=0;k<F;k++) acc += Wc[(size_t)(256+k)*256 + 128 + jc]*Wpy[k*F+i];
  M1[jc*F+i] = acc;
}

// K1: per (b, j-group of 4): one wave per feature row, segment max/mean over N=2080
__global__ __launch_bounds__(256) void k1_reduce(const float* __restrict__ nf,
                                                 float* __restrict__ glb, float* __restrict__ ave){
  const int jg = blockIdx.x, b = blockIdx.y;
  const int w = threadIdx.x>>6, lane = threadIdx.x&63;
  const int j = jg*4 + w;
  const float4* row = (const float4*)(nf + (size_t)(b*F + j)*NTOT);
  float cmax=-INFINITY, csum=0.f, smax=-INFINITY, ssum=0.f, emax=-INFINITY, esum=0.f;
  for(int n4 = lane; n4 < 520; n4 += 64){
    float4 v = row[n4];
    float mx = fmaxf(fmaxf(v.x,v.y), fmaxf(v.z,v.w));
    float sm = (v.x+v.y)+(v.z+v.w);
    if(n4 < 512){ cmax=fmaxf(cmax,mx); csum+=sm; }
    else if(n4 < 516){ smax=fmaxf(smax,mx); ssum+=sm; }
    else { emax=fmaxf(emax,mx); esum+=sm; }
  }
  cmax=wmax(cmax); csum=wsum(csum); smax=wmax(smax); ssum=wsum(ssum); emax=wmax(emax); esum=wsum(esum);
  if(lane==0){
    const int gb = b*4*F;
    glb[gb + j]       = fmaxf(cmax, fmaxf(smax,emax));
    glb[gb + F + j]   = cmax;
    glb[gb + 2*F + j] = smax;
    glb[gb + 3*F + j] = emax;
    float tS = csum+ssum+esum;
    ave[gb + j]       = tS / 2080.f;
    ave[gb + F + j]   = csum / 2048.f;
    ave[gb + 2*F + j] = ssum / 16.f;
    ave[gb + 3*F + j] = esum / 16.f;
  }
}

// K2a: per-batch small matvecs (transposed weights, thread-per-output)
__global__ __launch_bounds__(256) void k2a_prep(
    const float* __restrict__ WgT, const float* __restrict__ bg,
    const float* __restrict__ WcT, const float* __restrict__ Wc, const float* __restrict__ bc,
    const float* __restrict__ WpT, const float* __restrict__ bp,
    const float* __restrict__ Wpy,
    const float* __restrict__ glb, const float* __restrict__ ave,
    float* __restrict__ deglb_g, float* __restrict__ fa_g, float* __restrict__ cx,
    float* __restrict__ czc, float* __restrict__ vz, float* __restrict__ szc){
  const int b = blockIdx.x, tid = threadIdx.x;
  __shared__ float glb_s[512], ave_s[512];
  __shared__ float deglb_s[F], cvec_s[3*F], cpy_s[F];
  for(int i=tid;i<512;i+=256){ glb_s[i]=glb[b*512+i]; ave_s[i]=ave[b*512+i]; }
  __syncthreads();
  {
    const int j = tid&127;
    const float* src = (tid<128)? glb_s : ave_s;
    float a0=0.f,a1=0.f,a2=0.f,a3=0.f;
    for(int k=0;k<512;k+=4){
      a0 += WgT[(size_t)(k+0)*128+j]*src[k+0];
      a1 += WgT[(size_t)(k+1)*128+j]*src[k+1];
      a2 += WgT[(size_t)(k+2)*128+j]*src[k+2];
      a3 += WgT[(size_t)(k+3)*128+j]*src[k+3];
    }
    float d = (a0+a1)+(a2+a3) + bg[j];
    if(tid<128){ deglb_s[j]=d; deglb_g[b*F+j]=d; }
    else fa_g[b*F+j]=d;
  }
  __syncthreads();
  for(int i=tid;i<3*F;i+=256){
    float a0=0.f,a1=0.f,a2=0.f,a3=0.f;
    for(int k=0;k<F;k+=4){
      a0 += WcT[(size_t)(k+0)*384+i]*deglb_s[k+0];
      a1 += WcT[(size_t)(k+1)*384+i]*deglb_s[k+1];
      a2 += WcT[(size_t)(k+2)*384+i]*deglb_s[k+2];
      a3 += WcT[(size_t)(k+3)*384+i]*deglb_s[k+3];
    }
    float v = (a0+a1)+(a2+a3) + bc[i];
    cvec_s[i]=v;
    if(i<F) cx[b*F+i]=v;
  }
  __syncthreads();
  if(tid<128){
    const int j = tid;
    float a0=0.f,a1=0.f,a2=0.f,a3=0.f;
    for(int k=0;k<F;k+=4){
      a0 += WpT[(size_t)(k+0)*128+j]*cvec_s[128+k+0];
      a1 += WpT[(size_t)(k+1)*128+j]*cvec_s[128+k+1];
      a2 += WpT[(size_t)(k+2)*128+j]*cvec_s[128+k+2];
      a3 += WpT[(size_t)(k+3)*128+j]*cvec_s[128+k+3];
    }
    cpy_s[j] = (a0+a1)+(a2+a3) + bp[j];
  } else {
    const int j = tid-128;
    float a0=0.f,a1=0.f,a2=0.f,a3=0.f;
    for(int k=0;k<F;k+=4){
      a0 += Wpy[(size_t)(k+0)*128+j]*cvec_s[256+k+0];
      a1 += Wpy[(size_t)(k+1)*128+j]*cvec_s[256+k+1];
      a2 += Wpy[(size_t)(k+2)*128+j]*cvec_s[256+k+2];
      a3 += Wpy[(size_t)(k+3)*128+j]*cvec_s[256+k+3];
    }
    vz[b*F+j] = (a0+a1)+(a2+a3);
  }
  __syncthreads();
  if(tid<128){
    const int j = tid;
    float a0=0.f,a1=0.f,a2=0.f,a3=0.f;
    for(int k=0;k<F;k+=4){
      a0 += Wc[(size_t)(256+k+0)*256 + 128 + j]*cpy_s[k+0];
      a1 += Wc[(size_t)(256+k+1)*256 + 128 + j]*cpy_s[k+1];
      a2 += Wc[(size_t)(256+k+2)*256 + 128 + j]*cpy_s[k+2];
      a3 += Wc[(size_t)(256+k+3)*256 + 128 + j]*cpy_s[k+3];
    }
    czc[b*F+j] = (a0+a1)+(a2+a3);
  } else if(tid<192){
    const int lane = tid-128;
    float p = cpy_s[lane]*cvec_s[256+lane] + cpy_s[64+lane]*cvec_s[256+64+lane];
    p = wsum(p);
    if(lane==0) szc[b]=p;
  }
}

// K2c: per (agent a, batch b): af (WaT), afx, sx
__global__ __launch_bounds__(256) void k2c_agents(
    const float* __restrict__ nf, const float* __restrict__ WaT, const float* __restrict__ ba,
    const float* __restrict__ Wc,
    const float* __restrict__ deglb_g, const float* __restrict__ fa_g, const float* __restrict__ cx,
    float* __restrict__ afx, float* __restrict__ sx){
  const int a = blockIdx.x, b = blockIdx.y, tid = threadIdx.x;
  __shared__ float src_s[384];
  __shared__ float af_s[F], cx_s[F];
  if(tid<128){ src_s[tid] = deglb_g[b*F+tid]; cx_s[tid]=cx[b*F+tid]; }
  else if(a<16){
    const int j = tid-128;
    src_s[128+j] = nf[(size_t)(b*F+j)*NTOT + CN + a];
    src_s[256+j] = nf[(size_t)(b*F+j)*NTOT + CN + AN + a];
  }
  __syncthreads();
  if(a<16){
    if(tid<128){
      const int j = tid;
      float a0=0.f,a1=0.f,a2=0.f,a3=0.f;
      for(int k=0;k<384;k+=4){
        a0 += WaT[(size_t)(k+0)*128+j]*src_s[k+0];
        a1 += WaT[(size_t)(k+1)*128+j]*src_s[k+1];
        a2 += WaT[(size_t)(k+2)*128+j]*src_s[k+2];
        a3 += WaT[(size_t)(k+3)*128+j]*src_s[k+3];
      }
      af_s[j] = (a0+a1)+(a2+a3) + ba[j];
    }
  } else if(tid<128){
    af_s[tid] = fa_g[b*F+tid];
  }
  __syncthreads();
  if(tid<128){
    const int j = tid;
    float a0=0.f,a1=0.f,a2=0.f,a3=0.f;
    for(int i=0;i<F;i+=4){
      a0 += af_s[i+0]*Wc[(size_t)(i+0)*256 + 128 + j];
      a1 += af_s[i+1]*Wc[(size_t)(i+1)*256 + 128 + j];
      a2 += af_s[i+2]*Wc[(size_t)(i+2)*256 + 128 + j];
      a3 += af_s[i+3]*Wc[(size_t)(i+3)*256 + 128 + j];
    }
    afx[((size_t)b*NA+a)*F + j] = (a0+a1)+(a2+a3);
  } else if(tid<192){
    const int lane = tid-128;
    float p = af_s[lane]*cx_s[lane] + af_s[64+lane]*cx_s[64+lane];
    p = wsum(p);
    if(lane==0) sx[b*NA+a]=p;
  }
}

// K35: fused scores + chunk softmax + t-accum (R6 structure).
// afx is read DIRECTLY from global: wave-uniform address -> scalar loads (s_load),
// freeing the LDS pipe and shrinking the vector-issue stream.
__global__ __launch_bounds__(256) void k35_flash(const float* __restrict__ nf,
      const float* __restrict__ afx, const float* __restrict__ sx,
      float* __restrict__ pmax, float* __restrict__ psum, float* __restrict__ tpart){
  const int b = blockIdx.y, tid = threadIdx.x;
  const int chunk = blockIdx.x, c0 = chunk*CHK;
  __shared__ float sx_s[NA];
  __shared__ float at_s[NA*CHK];    // partial scores, then exp scores (8.5 KB)
  __shared__ float4 nf4_s[F*8];     // swizzled 32-city subtile (16 KB)
  __shared__ float red_s[2][NA];
  __shared__ float m_s[NA];
  if(tid<NA) sx_s[tid]=sx[b*NA+tid];
  __syncthreads();
  const int h = tid>>7, cl = tid&127, i0 = h*64;
  // phase 1: half-K score partials for city c0+cl; afx via uniform (scalar) loads
  float acc[NA];
  #pragma unroll
  for(int a=0;a<NA;a++) acc[a]=0.f;
  {
    const float* base = nf + (size_t)b*F*NTOT + (size_t)i0*NTOT + c0 + cl;
    const float* afxb = afx + (size_t)b*NA*F + i0;
    for(int q=0;q<16;q++){
      float v0 = base[(size_t)(q*4+0)*NTOT];
      float v1 = base[(size_t)(q*4+1)*NTOT];
      float v2 = base[(size_t)(q*4+2)*NTOT];
      float v3 = base[(size_t)(q*4+3)*NTOT];
      #pragma unroll
      for(int a=0;a<NA;a++){
        float4 w = *(const float4*)&afxb[a*F + q*4];
        acc[a] += w.x*v0 + w.y*v1 + w.z*v2 + w.w*v3;
      }
    }
  }
  if(h==0){
    #pragma unroll
    for(int a=0;a<NA;a++) at_s[a*CHK+cl] = acc[a];
  }
  __syncthreads();
  const int lane = tid&63;
  const float scale = 0.088388347648318447f;
  if(h==1){
    const int wq = (tid>>6)&1;
    #pragma unroll
    for(int a=0;a<NA;a++){
      acc[a] = (acc[a] + at_s[a*CHK+cl] + sx_s[a])*scale;
      float m = wmax(acc[a]);
      if(lane==0) red_s[wq][a]=m;
    }
  }
  __syncthreads();
  if(tid<NA){
    float m = fmaxf(red_s[0][tid], red_s[1][tid]);
    m_s[tid]=m;
    pmax[(b*NA+tid)*NCHK + chunk]=m;
  }
  __syncthreads();
  if(h==1){
    const int wq = (tid>>6)&1;
    #pragma unroll
    for(int a=0;a<NA;a++){
      float e = __expf(acc[a]-m_s[a]);
      at_s[a*CHK+cl]=e;
      float s = wsum(e);
      if(lane==0) red_s[wq][a]=s;
    }
  }
  __syncthreads();
  if(tid<NA)
    psum[(b*NA+tid)*NCHK + chunk] = red_s[0][tid]+red_s[1][tid];
  // phase 4: tpart over 4 subtiles of 32 cities (R6 structure)
  const int i = tid&127, A0 = h*8;
  float ta[9];
  #pragma unroll
  for(int a=0;a<9;a++) ta[a]=0.f;
  for(int s4=0;s4<4;s4++){
    const int csl = s4*32, cs = c0 + csl;
    __syncthreads();
    for(int idx=tid; idx<F*8; idx+=256){
      const int ii=idx>>3, g=idx&7;
      nf4_s[ii*8 + (g^(ii&7))] = *(const float4*)(nf + (size_t)(b*F+ii)*NTOT + cs + g*4);
    }
    __syncthreads();
    #pragma unroll 2
    for(int g=0; g<8; g++){
      float4 v = nf4_s[i*8 + (g^(i&7))];
      #pragma unroll
      for(int a=0;a<9;a++){
        float4 w = *(const float4*)&at_s[(A0+a)*CHK + csl + g*4];
        ta[a] += w.x*v.x + w.y*v.y + w.z*v.z + w.w*v.w;
      }
    }
  }
  float* dst = tpart + (size_t)chunk*64*NA*F + (size_t)b*NA*F;
  #pragma unroll
  for(int a=0;a<9;a++){
    if(h==0 || a>0) dst[(A0+a)*F + i] = ta[a];
  }
}

// K5c: per (b,a): combine 16 chunks with rescale; tn; afz = M1@tn + czc; sz = tn.vz + szc
__global__ __launch_bounds__(128) void k5c_final(const float* __restrict__ M1,
      const float* __restrict__ tpart, const float* __restrict__ pmax, const float* __restrict__ psum,
      const float* __restrict__ czc, const float* __restrict__ vz, const float* __restrict__ szc,
      float* __restrict__ afz, float* __restrict__ szv){
  const int a = blockIdx.x, b = blockIdx.y, tid = threadIdx.x;
  __shared__ float tn_s[F];
  const float* pm = pmax + (b*NA+a)*NCHK;
  const float* ps = psum + (b*NA+a)*NCHK;
  float M=-INFINITY;
  #pragma unroll
  for(int k=0;k<NCHK;k++) M = fmaxf(M, pm[k]);
  float w[NCHK]; float rs=0.f;
  #pragma unroll
  for(int k=0;k<NCHK;k++){ w[k]=__expf(pm[k]-M); rs += ps[k]*w[k]; }
  float s = 0.f;
  #pragma unroll
  for(int k=0;k<NCHK;k++) s += tpart[(size_t)k*64*NA*F + ((size_t)b*NA+a)*F + tid]*w[k];
  tn_s[tid] = s / rs;
  __syncthreads();
  float acc = 0.f;
  const float* m = M1 + (size_t)tid*F;
  for(int i=0;i<F;i++) acc += m[i]*tn_s[i];
  afz[((size_t)b*NA+a)*F + tid] = acc + czc[b*F+tid];
  float p = tn_s[tid]*vz[b*F+tid];
  p = wsum(p);
  __shared__ float red[2];
  if((tid&63)==0) red[tid>>6]=p;
  __syncthreads();
  if(tid==0) szv[b*NA+a] = red[0]+red[1] + szc[b];
}

// K6: logits + tanh + agent softmax (R6 structure); afz via uniform (scalar) loads.
__global__ __launch_bounds__(256) void k6_out(const float* __restrict__ nf, const float* __restrict__ afz,
      const float* __restrict__ szv, const int* __restrict__ step, float* __restrict__ out){
  const int b = blockIdx.y, tid = threadIdx.x;
  const int chunk = blockIdx.x, c0 = chunk*CHK;
  __shared__ float sz_s[NA];
  __shared__ float sc_s[NA*CHK];
  if(tid<NA) sz_s[tid]=szv[b*NA+tid];
  __syncthreads();
  const int h = tid>>7, cl = tid&127, i0 = h*64;
  float acc[NA];
  #pragma unroll
  for(int a=0;a<NA;a++) acc[a]=0.f;
  {
    const float* base = nf + (size_t)b*F*NTOT + (size_t)i0*NTOT + c0 + cl;
    const float* afzb = afz + (size_t)b*NA*F + i0;
    for(int q=0;q<16;q++){
      float v0 = base[(size_t)(q*4+0)*NTOT];
      float v1 = base[(size_t)(q*4+1)*NTOT];
      float v2 = base[(size_t)(q*4+2)*NTOT];
      float v3 = base[(size_t)(q*4+3)*NTOT];
      #pragma unroll
      for(int a=0;a<NA;a++){
        float4 w = *(const float4*)&afzb[a*F + q*4];
        acc[a] += w.x*v0 + w.y*v1 + w.z*v2 + w.w*v3;
      }
    }
  }
  if(h==0){
    #pragma unroll
    for(int a=0;a<NA;a++) sc_s[a*CHK+cl] = acc[a];
  }
  __syncthreads();
  if(h==1){
    const int A = (step[0] > 0) ? NA : AN;
    const float scale = 0.088388347648318447f;
    float l[NA];
    #pragma unroll
    for(int a=0;a<NA;a++)
      l[a] = tanhf((acc[a] + sc_s[a*CHK+cl] + sz_s[a])*scale)*10.f;
    const bool f17 = (A==NA);
    float m = l[0];
    #pragma unroll
    for(int a=1;a<AN;a++) m = fmaxf(m,l[a]);
    if(f17) m = fmaxf(m,l[16]);
    float ssum=0.f;
    #pragma unroll
    for(int a=0;a<AN;a++){ float e=__expf(l[a]-m); l[a]=e; ssum+=e; }
    float e16=__expf(l[16]-m);
    if(f17){ ssum+=e16; }
    const float inv = 1.f/ssum;
    float* op = out + (size_t)(b*CN + c0 + cl)*A;
    #pragma unroll
    for(int a=0;a<AN;a++) op[a]=l[a]*inv;
    if(f17) op[16]=e16*inv;
  }
}

extern "C" void kernel_launch(void* const* d_in, const int* in_sizes, int n_in,
                              void* d_out, int out_size, void* d_ws, size_t ws_size,
                              hipStream_t stream){
  const float* nf = (const float*)d_in[0];
  const float* Wg = (const float*)d_in[1];
  const float* bg = (const float*)d_in[2];
  const float* Wc = (const float*)d_in[3];
  const float* bc = (const float*)d_in[4];
  const float* Wa = (const float*)d_in[5];
  const float* ba = (const float*)d_in[6];
  const float* Wp = (const float*)d_in[7];
  const float* bp = (const float*)d_in[8];
  const int*  step = (const int*)d_in[9];
  float* out = (float*)d_out;

  float* ws = (float*)d_ws;
  float* glb     = ws;                    // 64*512
  float* ave     = glb + 64*512;          // 64*512
  float* afx     = ave + 64*512;          // 64*17*128
  float* sx      = afx + 64*NA*F;         // 64*17
  float* Wpy     = sx + 64*NA;            // 128*128
  float* M1      = Wpy + F*F;             // 128*128
  float* czc     = M1 + F*F;              // 64*128
  float* vz      = czc + 64*F;            // 64*128
  float* szc     = vz + 64*F;             // 64
  float* pmax    = szc + 64;              // 64*17*16
  float* psum    = pmax + 64*NA*NCHK;     // 64*17*16
  float* deglb_g = psum + 64*NA*NCHK;     // 64*128
  float* fa_g    = deglb_g + 64*F;        // 64*128
  float* cx      = fa_g + 64*F;           // 64*128
  float* WgT     = cx + 64*F;             // 512*128
  float* WcT     = WgT + 512*F;           // 256*384
  float* WpT     = WcT + 256*384;         // 128*128
  float* WaT     = WpT + F*F;             // 384*128
  float* tpart   = WaT + 384*F;           // 16*64*17*128
  float* afz     = tpart + (size_t)NCHK*64*NA*F;  // 64*17*128
  float* szv     = afz + 64*NA*F;         // 64*17

  k0t_transpose<<<dim3(16,12,4),256,0,stream>>>(Wg,Wc,Wp,Wa, WgT,WcT,WpT,WaT);
  k0a_wpy<<<F,F,0,stream>>>(Wp, Wc, Wpy);
  k0b_m1<<<F,F,0,stream>>>(Wc, Wpy, M1);
  k1_reduce<<<dim3(32,64),256,0,stream>>>(nf, glb, ave);
  k2a_prep<<<64,256,0,stream>>>(WgT,bg, WcT,Wc,bc, WpT,bp, Wpy, glb,ave, deglb_g,fa_g,cx, czc,vz,szc);
  k2c_agents<<<dim3(NA,64),256,0,stream>>>(nf, WaT,ba,Wc, deglb_g,fa_g,cx, afx,sx);
  k35_flash<<<dim3(NCHK,64),256,0,stream>>>(nf, afx, sx, pmax, psum, tpart);
  k5c_final<<<dim3(NA,64),128,0,stream>>>(M1, tpart, pmax, psum, czc, vz, szc, afz, szv);
  k6_out<<<dim3(NCHK,64),256,0,stream>>>(nf, afz, szv, step, out);
}

// Round 12
// 153.007 us; speedup vs baseline: 1.1827x; 1.1827x over previous
//
#include <hip/hip_runtime.h>
#include <math.h>

#define F 128
#define NTOT 2080
#define CN 2048
#define AN 16
#define NA 17   // max agents (step>0)
#define CHK 128 // cities per chunk (k35/k6)
#define NCHK 16 // CN/CHK

__device__ __forceinline__ float wmax(float v){
  #pragma unroll
  for(int m=32;m;m>>=1) v = fmaxf(v, __shfl_xor(v, m, 64));
  return v;
}
__device__ __forceinline__ float wsum(float v){
  #pragma unroll
  for(int m=32;m;m>>=1) v += __shfl_xor(v, m, 64);
  return v;
}

// K0t: tiled transposes of Wg(128x512), Wc(384x256), Wp(128x128), Wa(128x384)
__global__ __launch_bounds__(256) void k0t_transpose(
      const float* __restrict__ Wg, const float* __restrict__ Wc,
      const float* __restrict__ Wp, const float* __restrict__ Wa,
      float* __restrict__ WgT, float* __restrict__ WcT,
      float* __restrict__ WpT, float* __restrict__ WaT){
  __shared__ float tile[32][33];
  const int z = blockIdx.z;
  const float* src; float* dst; int R, C;
  if(z==0){ src=Wg; dst=WgT; R=128; C=512; }
  else if(z==1){ src=Wc; dst=WcT; R=384; C=256; }
  else if(z==2){ src=Wp; dst=WpT; R=128; C=128; }
  else { src=Wa; dst=WaT; R=128; C=384; }
  const int c0 = blockIdx.x*32, r0 = blockIdx.y*32;
  if(c0>=C || r0>=R) return;
  const int tx = threadIdx.x&31, ty = threadIdx.x>>5;   // 32x8
  #pragma unroll
  for(int rr=0;rr<4;rr++)
    tile[ty+rr*8][tx] = src[(size_t)(r0+ty+rr*8)*C + c0 + tx];
  __syncthreads();
  #pragma unroll
  for(int rr=0;rr<4;rr++)
    dst[(size_t)(c0+ty+rr*8)*R + r0 + tx] = tile[tx][ty+rr*8];
}

// K0a: Wpy = Wp @ Wcy2   (Wpy[k,i] = sum_j Wp[k,j]*Wc[128+j, 128+i])
__global__ __launch_bounds__(128) void k0a_wpy(const float* __restrict__ Wp, const float* __restrict__ Wc,
                                               float* __restrict__ Wpy){
  const int k = blockIdx.x, i = threadIdx.x;
  float acc = 0.f;
  const float* wp = Wp + (size_t)k*F;
  for(int j=0;j<F;j++) acc += wp[j]*Wc[(size_t)(128+j)*256 + 128 + i];
  Wpy[k*F+i] = acc;
}

// K0b: M1 = Wcz2^T @ Wpy  (M1[jc,i] = sum_k Wc[256+k, 128+jc]*Wpy[k,i])
__global__ __launch_bounds__(128) void k0b_m1(const float* __restrict__ Wc, const float* __restrict__ Wpy,
                                              float* __restrict__ M1){
  const int jc = blockIdx.x, i = threadIdx.x;
  float acc = 0.f;
  for(int k=0;k<F;k++) acc += Wc[(size_t)(256+k)*256 + 128 + jc]*Wpy[k*F+i];
  M1[jc*F+i] = acc;
}

// K1: per (b, j-group of 4): one wave per feature row, segment max/mean over N=2080
__global__ __launch_bounds__(256) void k1_reduce(const float* __restrict__ nf,
                                                 float* __restrict__ glb, float* __restrict__ ave){
  const int jg = blockIdx.x, b = blockIdx.y;
  const int w = threadIdx.x>>6, lane = threadIdx.x&63;
  const int j = jg*4 + w;
  const float4* row = (const float4*)(nf + (size_t)(b*F + j)*NTOT);
  float cmax=-INFINITY, csum=0.f, smax=-INFINITY, ssum=0.f, emax=-INFINITY, esum=0.f;
  for(int n4 = lane; n4 < 520; n4 += 64){
    float4 v = row[n4];
    float mx = fmaxf(fmaxf(v.x,v.y), fmaxf(v.z,v.w));
    float sm = (v.x+v.y)+(v.z+v.w);
    if(n4 < 512){ cmax=fmaxf(cmax,mx); csum+=sm; }
    else if(n4 < 516){ smax=fmaxf(smax,mx); ssum+=sm; }
    else { emax=fmaxf(emax,mx); esum+=sm; }
  }
  cmax=wmax(cmax); csum=wsum(csum); smax=wmax(smax); ssum=wsum(ssum); emax=wmax(emax); esum=wsum(esum);
  if(lane==0){
    const int gb = b*4*F;
    glb[gb + j]       = fmaxf(cmax, fmaxf(smax,emax));
    glb[gb + F + j]   = cmax;
    glb[gb + 2*F + j] = smax;
    glb[gb + 3*F + j] = emax;
    float tS = csum+ssum+esum;
    ave[gb + j]       = tS / 2080.f;
    ave[gb + F + j]   = csum / 2048.f;
    ave[gb + 2*F + j] = ssum / 16.f;
    ave[gb + 3*F + j] = esum / 16.f;
  }
}

// K2a: per-batch: deglb/fa (WgT, thread-per-j), cvec (WcT), cpy (WpT) + vz, czc, szc
__global__ __launch_bounds__(256) void k2a_prep(
    const float* __restrict__ WgT, const float* __restrict__ bg,
    const float* __restrict__ WcT, const float* __restrict__ Wc, const float* __restrict__ bc,
    const float* __restrict__ WpT, const float* __restrict__ bp,
    const float* __restrict__ Wpy,
    const float* __restrict__ glb, const float* __restrict__ ave,
    float* __restrict__ deglb_g, float* __restrict__ fa_g, float* __restrict__ cx,
    float* __restrict__ czc, float* __restrict__ vz, float* __restrict__ szc){
  const int b = blockIdx.x, tid = threadIdx.x;
  __shared__ float glb_s[512], ave_s[512];
  __shared__ float deglb_s[F], cvec_s[3*F], cpy_s[F];
  for(int i=tid;i<512;i+=256){ glb_s[i]=glb[b*512+i]; ave_s[i]=ave[b*512+i]; }
  __syncthreads();
  { // deglb (threads 0..127) / fa (threads 128..255): same WgT addresses -> L1 hits
    const int j = tid&127;
    const float* src = (tid<128)? glb_s : ave_s;
    float a0=0.f,a1=0.f,a2=0.f,a3=0.f;
    for(int k=0;k<512;k+=4){
      a0 += WgT[(size_t)(k+0)*128+j]*src[k+0];
      a1 += WgT[(size_t)(k+1)*128+j]*src[k+1];
      a2 += WgT[(size_t)(k+2)*128+j]*src[k+2];
      a3 += WgT[(size_t)(k+3)*128+j]*src[k+3];
    }
    float d = (a0+a1)+(a2+a3) + bg[j];
    if(tid<128){ deglb_s[j]=d; deglb_g[b*F+j]=d; }
    else fa_g[b*F+j]=d;
  }
  __syncthreads();
  // cvec[i] = bc[i] + sum_{k<128} WcT[k*384+i]*deglb[k]
  for(int i=tid;i<3*F;i+=256){
    float a0=0.f,a1=0.f,a2=0.f,a3=0.f;
    for(int k=0;k<F;k+=4){
      a0 += WcT[(size_t)(k+0)*384+i]*deglb_s[k+0];
      a1 += WcT[(size_t)(k+1)*384+i]*deglb_s[k+1];
      a2 += WcT[(size_t)(k+2)*384+i]*deglb_s[k+2];
      a3 += WcT[(size_t)(k+3)*384+i]*deglb_s[k+3];
    }
    float v = (a0+a1)+(a2+a3) + bc[i];
    cvec_s[i]=v;
    if(i<F) cx[b*F+i]=v;
  }
  __syncthreads();
  if(tid<128){ // cpy[j] = bp[j] + Wp[j,:] . consty
    const int j = tid;
    float a0=0.f,a1=0.f,a2=0.f,a3=0.f;
    for(int k=0;k<F;k+=4){
      a0 += WpT[(size_t)(k+0)*128+j]*cvec_s[128+k+0];
      a1 += WpT[(size_t)(k+1)*128+j]*cvec_s[128+k+1];
      a2 += WpT[(size_t)(k+2)*128+j]*cvec_s[128+k+2];
      a3 += WpT[(size_t)(k+3)*128+j]*cvec_s[128+k+3];
    }
    cpy_s[j] = (a0+a1)+(a2+a3) + bp[j];
  } else { // vz[j] = Wpy^T @ cz (independent of cpy)
    const int j = tid-128;
    float a0=0.f,a1=0.f,a2=0.f,a3=0.f;
    for(int k=0;k<F;k+=4){
      a0 += Wpy[(size_t)(k+0)*128+j]*cvec_s[256+k+0];
      a1 += Wpy[(size_t)(k+1)*128+j]*cvec_s[256+k+1];
      a2 += Wpy[(size_t)(k+2)*128+j]*cvec_s[256+k+2];
      a3 += Wpy[(size_t)(k+3)*128+j]*cvec_s[256+k+3];
    }
    vz[b*F+j] = (a0+a1)+(a2+a3);
  }
  __syncthreads();
  if(tid<128){ // czc[j] = Wcz2^T @ cpy (coalesced over j in original Wc)
    const int j = tid;
    float a0=0.f,a1=0.f,a2=0.f,a3=0.f;
    for(int k=0;k<F;k+=4){
      a0 += Wc[(size_t)(256+k+0)*256 + 128 + j]*cpy_s[k+0];
      a1 += Wc[(size_t)(256+k+1)*256 + 128 + j]*cpy_s[k+1];
      a2 += Wc[(size_t)(256+k+2)*256 + 128 + j]*cpy_s[k+2];
      a3 += Wc[(size_t)(256+k+3)*256 + 128 + j]*cpy_s[k+3];
    }
    czc[b*F+j] = (a0+a1)+(a2+a3);
  } else if(tid<192){ // szc = cpy . cz
    const int lane = tid-128;
    float p = cpy_s[lane]*cvec_s[256+lane] + cpy_s[64+lane]*cvec_s[256+64+lane];
    p = wsum(p);
    if(lane==0) szc[b]=p;
  }
}

// K2c: per (agent a, batch b): af (WaT, thread-per-j), afx, sx
__global__ __launch_bounds__(256) void k2c_agents(
    const float* __restrict__ nf, const float* __restrict__ WaT, const float* __restrict__ ba,
    const float* __restrict__ Wc,
    const float* __restrict__ deglb_g, const float* __restrict__ fa_g, const float* __restrict__ cx,
    float* __restrict__ afx, float* __restrict__ sx){
  const int a = blockIdx.x, b = blockIdx.y, tid = threadIdx.x;
  __shared__ float src_s[384];   // [deglb | a_start_a | a_end_a]
  __shared__ float af_s[F], cx_s[F];
  if(tid<128){ src_s[tid] = deglb_g[b*F+tid]; cx_s[tid]=cx[b*F+tid]; }
  else if(a<16){
    const int j = tid-128;
    src_s[128+j] = nf[(size_t)(b*F+j)*NTOT + CN + a];
    src_s[256+j] = nf[(size_t)(b*F+j)*NTOT + CN + AN + a];
  }
  __syncthreads();
  if(a<16){
    if(tid<128){
      const int j = tid;
      float a0=0.f,a1=0.f,a2=0.f,a3=0.f;
      for(int k=0;k<384;k+=4){
        a0 += WaT[(size_t)(k+0)*128+j]*src_s[k+0];
        a1 += WaT[(size_t)(k+1)*128+j]*src_s[k+1];
        a2 += WaT[(size_t)(k+2)*128+j]*src_s[k+2];
        a3 += WaT[(size_t)(k+3)*128+j]*src_s[k+3];
      }
      af_s[j] = (a0+a1)+(a2+a3) + ba[j];
    }
  } else if(tid<128){
    af_s[tid] = fa_g[b*F+tid];
  }
  __syncthreads();
  if(tid<128){ // afx[j] = sum_i af[i]*Wc[i, 128+j]  (coalesced over j)
    const int j = tid;
    float a0=0.f,a1=0.f,a2=0.f,a3=0.f;
    for(int i=0;i<F;i+=4){
      a0 += af_s[i+0]*Wc[(size_t)(i+0)*256 + 128 + j];
      a1 += af_s[i+1]*Wc[(size_t)(i+1)*256 + 128 + j];
      a2 += af_s[i+2]*Wc[(size_t)(i+2)*256 + 128 + j];
      a3 += af_s[i+3]*Wc[(size_t)(i+3)*256 + 128 + j];
    }
    afx[((size_t)b*NA+a)*F + j] = (a0+a1)+(a2+a3);
  } else if(tid<192){ // sx = af . constx
    const int lane = tid-128;
    float p = af_s[lane]*cx_s[lane] + af_s[64+lane]*cx_s[64+lane];
    p = wsum(p);
    if(lane==0) sx[b*NA+a]=p;
  }
}

// K35: fused scores + chunk softmax + t-accum. Chunk=128 cities, split-K halves.
__global__ __launch_bounds__(256) void k35_flash(const float* __restrict__ nf,
      const float* __restrict__ afx, const float* __restrict__ sx,
      float* __restrict__ pmax, float* __restrict__ psum, float* __restrict__ tpart){
  const int b = blockIdx.y, tid = threadIdx.x;
  const int chunk = blockIdx.x, c0 = chunk*CHK;
  __shared__ float afx_s[NA*F];
  __shared__ float sx_s[NA];
  __shared__ float at_s[NA*CHK];   // partial scores, then exp scores
  __shared__ float4 nf4_s[F*8];    // swizzled 32-city subtile
  __shared__ float red_s[2][NA];
  __shared__ float m_s[NA];
  for(int o=tid;o<NA*F;o+=256) afx_s[o]=afx[(size_t)b*NA*F+o];
  if(tid<NA) sx_s[tid]=sx[b*NA+tid];
  __syncthreads();
  const int h = tid>>7, cl = tid&127, i0 = h*64;
  // phase 1: half-K score partials for city c0+cl (float4 afx broadcast reads)
  float acc[NA];
  #pragma unroll
  for(int a=0;a<NA;a++) acc[a]=0.f;
  {
    const float* base = nf + (size_t)b*F*NTOT + (size_t)i0*NTOT + c0 + cl;
    for(int q=0;q<16;q++){
      float v0 = base[(size_t)(q*4+0)*NTOT];
      float v1 = base[(size_t)(q*4+1)*NTOT];
      float v2 = base[(size_t)(q*4+2)*NTOT];
      float v3 = base[(size_t)(q*4+3)*NTOT];
      #pragma unroll
      for(int a=0;a<NA;a++){
        float4 w = *(const float4*)&afx_s[a*F + i0 + q*4];
        acc[a] += w.x*v0 + w.y*v1 + w.z*v2 + w.w*v3;
      }
    }
  }
  if(h==0){
    #pragma unroll
    for(int a=0;a<NA;a++) at_s[a*CHK+cl] = acc[a];
  }
  __syncthreads();
  const int lane = tid&63;
  const float scale = 0.088388347648318447f;
  if(h==1){
    const int wq = (tid>>6)&1;
    #pragma unroll
    for(int a=0;a<NA;a++){
      acc[a] = (acc[a] + at_s[a*CHK+cl] + sx_s[a])*scale;
      float m = wmax(acc[a]);
      if(lane==0) red_s[wq][a]=m;
    }
  }
  __syncthreads();
  if(tid<NA){
    float m = fmaxf(red_s[0][tid], red_s[1][tid]);
    m_s[tid]=m;
    pmax[(b*NA+tid)*NCHK + chunk]=m;
  }
  __syncthreads();
  if(h==1){
    const int wq = (tid>>6)&1;
    #pragma unroll
    for(int a=0;a<NA;a++){
      float e = __expf(acc[a]-m_s[a]);
      at_s[a*CHK+cl]=e;
      float s = wsum(e);
      if(lane==0) red_s[wq][a]=s;
    }
  }
  __syncthreads();
  if(tid<NA)
    psum[(b*NA+tid)*NCHK + chunk] = red_s[0][tid]+red_s[1][tid];
  // phase 4: tpart over 4 subtiles of 32 cities
  const int i = tid&127, A0 = h*8;
  float ta[9];
  #pragma unroll
  for(int a=0;a<9;a++) ta[a]=0.f;
  for(int s4=0;s4<4;s4++){
    const int csl = s4*32, cs = c0 + csl;
    __syncthreads();
    for(int idx=tid; idx<F*8; idx+=256){
      const int ii=idx>>3, g=idx&7;
      nf4_s[ii*8 + (g^(ii&7))] = *(const float4*)(nf + (size_t)(b*F+ii)*NTOT + cs + g*4);
    }
    __syncthreads();
    #pragma unroll 2
    for(int g=0; g<8; g++){
      float4 v = nf4_s[i*8 + (g^(i&7))];
      #pragma unroll
      for(int a=0;a<9;a++){
        float4 w = *(const float4*)&at_s[(A0+a)*CHK + csl + g*4];
        ta[a] += w.x*v.x + w.y*v.y + w.z*v.z + w.w*v.w;
      }
    }
  }
  float* dst = tpart + (size_t)chunk*64*NA*F + (size_t)b*NA*F;
  #pragma unroll
  for(int a=0;a<9;a++){
    if(h==0 || a>0) dst[(A0+a)*F + i] = ta[a];
  }
}

// K5c: per (b,a): combine 16 chunks with rescale; tn; afz = M1@tn + czc; sz = tn.vz + szc
__global__ __launch_bounds__(128) void k5c_final(const float* __restrict__ M1,
      const float* __restrict__ tpart, const float* __restrict__ pmax, const float* __restrict__ psum,
      const float* __restrict__ czc, const float* __restrict__ vz, const float* __restrict__ szc,
      float* __restrict__ afz, float* __restrict__ szv){
  const int a = blockIdx.x, b = blockIdx.y, tid = threadIdx.x;
  __shared__ float tn_s[F];
  const float* pm = pmax + (b*NA+a)*NCHK;
  const float* ps = psum + (b*NA+a)*NCHK;
  float M=-INFINITY;
  #pragma unroll
  for(int k=0;k<NCHK;k++) M = fmaxf(M, pm[k]);
  float w[NCHK]; float rs=0.f;
  #pragma unroll
  for(int k=0;k<NCHK;k++){ w[k]=__expf(pm[k]-M); rs += ps[k]*w[k]; }
  float s = 0.f;
  #pragma unroll
  for(int k=0;k<NCHK;k++) s += tpart[(size_t)k*64*NA*F + ((size_t)b*NA+a)*F + tid]*w[k];
  tn_s[tid] = s / rs;
  __syncthreads();
  float acc = 0.f;
  const float* m = M1 + (size_t)tid*F;
  for(int i=0;i<F;i++) acc += m[i]*tn_s[i];
  afz[((size_t)b*NA+a)*F + tid] = acc + czc[b*F+tid];
  float p = tn_s[tid]*vz[b*F+tid];
  p = wsum(p);
  __shared__ float red[2];
  if((tid&63)==0) red[tid>>6]=p;
  __syncthreads();
  if(tid==0) szv[b*NA+a] = red[0]+red[1] + szc[b];
}

// K6: logits + tanh + agent softmax. Chunk=128 cities, split-K halves, float4 afz reads.
__global__ __launch_bounds__(256) void k6_out(const float* __restrict__ nf, const float* __restrict__ afz,
      const float* __restrict__ szv, const int* __restrict__ step, float* __restrict__ out){
  const int b = blockIdx.y, tid = threadIdx.x;
  const int chunk = blockIdx.x, c0 = chunk*CHK;
  __shared__ float afz_s[NA*F]; __shared__ float sz_s[NA];
  __shared__ float sc_s[NA*CHK];
  for(int o=tid;o<NA*F;o+=256) afz_s[o]=afz[(size_t)b*NA*F+o];
  if(tid<NA) sz_s[tid]=szv[b*NA+tid];
  __syncthreads();
  const int h = tid>>7, cl = tid&127, i0 = h*64;
  float acc[NA];
  #pragma unroll
  for(int a=0;a<NA;a++) acc[a]=0.f;
  {
    const float* base = nf + (size_t)b*F*NTOT + (size_t)i0*NTOT + c0 + cl;
    for(int q=0;q<16;q++){
      float v0 = base[(size_t)(q*4+0)*NTOT];
      float v1 = base[(size_t)(q*4+1)*NTOT];
      float v2 = base[(size_t)(q*4+2)*NTOT];
      float v3 = base[(size_t)(q*4+3)*NTOT];
      #pragma unroll
      for(int a=0;a<NA;a++){
        float4 w = *(const float4*)&afz_s[a*F + i0 + q*4];
        acc[a] += w.x*v0 + w.y*v1 + w.z*v2 + w.w*v3;
      }
    }
  }
  if(h==0){
    #pragma unroll
    for(int a=0;a<NA;a++) sc_s[a*CHK+cl] = acc[a];
  }
  __syncthreads();
  if(h==1){
    const int A = (step[0] > 0) ? NA : AN;
    const float scale = 0.088388347648318447f;
    float l[NA];
    #pragma unroll
    for(int a=0;a<NA;a++)
      l[a] = tanhf((acc[a] + sc_s[a*CHK+cl] + sz_s[a])*scale)*10.f;
    const bool f17 = (A==NA);
    float m = l[0];
    #pragma unroll
    for(int a=1;a<AN;a++) m = fmaxf(m,l[a]);
    if(f17) m = fmaxf(m,l[16]);
    float ssum=0.f;
    #pragma unroll
    for(int a=0;a<AN;a++){ float e=__expf(l[a]-m); l[a]=e; ssum+=e; }
    float e16=__expf(l[16]-m);
    if(f17){ ssum+=e16; }
    const float inv = 1.f/ssum;
    float* op = out + (size_t)(b*CN + c0 + cl)*A;
    #pragma unroll
    for(int a=0;a<AN;a++) op[a]=l[a]*inv;
    if(f17) op[16]=e16*inv;
  }
}

extern "C" void kernel_launch(void* const* d_in, const int* in_sizes, int n_in,
                              void* d_out, int out_size, void* d_ws, size_t ws_size,
                              hipStream_t stream){
  const float* nf = (const float*)d_in[0];
  const float* Wg = (const float*)d_in[1];
  const float* bg = (const float*)d_in[2];
  const float* Wc = (const float*)d_in[3];
  const float* bc = (const float*)d_in[4];
  const float* Wa = (const float*)d_in[5];
  const float* ba = (const float*)d_in[6];
  const float* Wp = (const float*)d_in[7];
  const float* bp = (const float*)d_in[8];
  const int*  step = (const int*)d_in[9];
  float* out = (float*)d_out;

  float* ws = (float*)d_ws;
  float* glb     = ws;                    // 64*512
  float* ave     = glb + 64*512;          // 64*512
  float* afx     = ave + 64*512;          // 64*17*128
  float* sx      = afx + 64*NA*F;         // 64*17
  float* Wpy     = sx + 64*NA;            // 128*128
  float* M1      = Wpy + F*F;             // 128*128
  float* czc     = M1 + F*F;              // 64*128
  float* vz      = czc + 64*F;            // 64*128
  float* szc     = vz + 64*F;             // 64
  float* pmax    = szc + 64;              // 64*17*16
  float* psum    = pmax + 64*NA*NCHK;     // 64*17*16
  float* deglb_g = psum + 64*NA*NCHK;     // 64*128
  float* fa_g    = deglb_g + 64*F;        // 64*128
  float* cx      = fa_g + 64*F;           // 64*128
  float* WgT     = cx + 64*F;             // 512*128
  float* WcT     = WgT + 512*F;           // 256*384
  float* WpT     = WcT + 256*384;         // 128*128
  float* WaT     = WpT + F*F;             // 384*128
  float* tpart   = WaT + 384*F;           // 16*64*17*128
  float* afz     = tpart + (size_t)NCHK*64*NA*F;  // 64*17*128
  float* szv     = afz + 64*NA*F;         // 64*17

  k0t_transpose<<<dim3(16,12,4),256,0,stream>>>(Wg,Wc,Wp,Wa, WgT,WcT,WpT,WaT);
  k0a_wpy<<<F,F,0,stream>>>(Wp, Wc, Wpy);
  k0b_m1<<<F,F,0,stream>>>(Wc, Wpy, M1);
  k1_reduce<<<dim3(32,64),256,0,stream>>>(nf, glb, ave);
  k2a_prep<<<64,256,0,stream>>>(WgT,bg, WcT,Wc,bc, WpT,bp, Wpy, glb,ave, deglb_g,fa_g,cx, czc,vz,szc);
  k2c_agents<<<dim3(NA,64),256,0,stream>>>(nf, WaT,ba,Wc, deglb_g,fa_g,cx, afx,sx);
  k35_flash<<<dim3(NCHK,64),256,0,stream>>>(nf, afx, sx, pmax, psum, tpart);
  k5c_final<<<dim3(NA,64),128,0,stream>>>(M1, tpart, pmax, psum, czc, vz, szc, afz, szv);
  k6_out<<<dim3(NCHK,64),256,0,stream>>>(nf, afz, szv, step, out);
}

// Round 13
// 136.526 us; speedup vs baseline: 1.3255x; 1.1207x over previous
//
#include <hip/hip_runtime.h>
#include <math.h>
#include <stdint.h>

#define F 128
#define NTOT 2080
#define CN 2048
#define AN 16
#define NA 17   // max agents (step>0)
#define CHK 128 // cities per chunk (k35/k6)
#define NCHK 16 // CN/CHK

__device__ __forceinline__ float wmax(float v){
  #pragma unroll
  for(int m=32;m;m>>=1) v = fmaxf(v, __shfl_xor(v, m, 64));
  return v;
}
__device__ __forceinline__ float wsum(float v){
  #pragma unroll
  for(int m=32;m;m>>=1) v += __shfl_xor(v, m, 64);
  return v;
}

// K_pre1: fused {k0t transposes | k0a Wpy | k1 reductions} — independent blocks.
// blocks 0..767: transposes; 768..831: Wpy (2 rows each); 832..2879: k1 (jg,b).
__global__ __launch_bounds__(256) void k_pre1(
      const float* __restrict__ nf,
      const float* __restrict__ Wg, const float* __restrict__ Wc,
      const float* __restrict__ Wp, const float* __restrict__ Wa,
      float* __restrict__ WgT, float* __restrict__ WcT,
      float* __restrict__ WpT, float* __restrict__ WaT,
      float* __restrict__ Wpy,
      float* __restrict__ glb, float* __restrict__ ave){
  __shared__ float tile[32][33];
  const int bx = blockIdx.x, tid = threadIdx.x;
  if(bx < 768){
    const int z = bx/192, rem = bx%192;
    const int c0 = (rem&15)*32, r0 = (rem>>4)*32;
    const float* src; float* dst; int R, C;
    if(z==0){ src=Wg; dst=WgT; R=128; C=512; }
    else if(z==1){ src=Wc; dst=WcT; R=384; C=256; }
    else if(z==2){ src=Wp; dst=WpT; R=128; C=128; }
    else { src=Wa; dst=WaT; R=128; C=384; }
    if(c0>=C || r0>=R) return;
    const int tx = tid&31, ty = tid>>5;   // 32x8
    #pragma unroll
    for(int rr=0;rr<4;rr++)
      tile[ty+rr*8][tx] = src[(size_t)(r0+ty+rr*8)*C + c0 + tx];
    __syncthreads();
    #pragma unroll
    for(int rr=0;rr<4;rr++)
      dst[(size_t)(c0+ty+rr*8)*R + r0 + tx] = tile[tx][ty+rr*8];
    return;
  }
  if(bx < 832){
    // k0a: Wpy[k,i] = sum_j Wp[k,j]*Wc[128+j, 128+i]; 2 rows per block
    const int k = (bx-768)*2 + (tid>>7);
    const int i = tid&127;
    float acc = 0.f;
    const float* wp = Wp + (size_t)k*F;
    for(int j=0;j<F;j++) acc += wp[j]*Wc[(size_t)(128+j)*256 + 128 + i];
    Wpy[k*F+i] = acc;
    return;
  }
  // k1: per (b, j-group of 4): one wave per feature row
  {
    const int r = bx-832;
    const int jg = r&31, b = r>>5;
    const int w = tid>>6, lane = tid&63;
    const int j = jg*4 + w;
    const float4* row = (const float4*)(nf + (size_t)(b*F + j)*NTOT);
    float cmax=-INFINITY, csum=0.f, smax=-INFINITY, ssum=0.f, emax=-INFINITY, esum=0.f;
    for(int n4 = lane; n4 < 520; n4 += 64){
      float4 v = row[n4];
      float mx = fmaxf(fmaxf(v.x,v.y), fmaxf(v.z,v.w));
      float sm = (v.x+v.y)+(v.z+v.w);
      if(n4 < 512){ cmax=fmaxf(cmax,mx); csum+=sm; }
      else if(n4 < 516){ smax=fmaxf(smax,mx); ssum+=sm; }
      else { emax=fmaxf(emax,mx); esum+=sm; }
    }
    cmax=wmax(cmax); csum=wsum(csum); smax=wmax(smax); ssum=wsum(ssum); emax=wmax(emax); esum=wsum(esum);
    if(lane==0){
      const int gb = b*4*F;
      glb[gb + j]       = fmaxf(cmax, fmaxf(smax,emax));
      glb[gb + F + j]   = cmax;
      glb[gb + 2*F + j] = smax;
      glb[gb + 3*F + j] = emax;
      float tS = csum+ssum+esum;
      ave[gb + j]       = tS / 2080.f;
      ave[gb + F + j]   = csum / 2048.f;
      ave[gb + 2*F + j] = ssum / 16.f;
      ave[gb + 3*F + j] = esum / 16.f;
    }
  }
}

// K_pre2: fused {k2a per-batch prep (blocks 0..63) | k0b M1 rows (blocks 64..127)}
__global__ __launch_bounds__(256) void k_pre2(
    const float* __restrict__ WgT, const float* __restrict__ bg,
    const float* __restrict__ WcT, const float* __restrict__ Wc, const float* __restrict__ bc,
    const float* __restrict__ WpT, const float* __restrict__ bp,
    const float* __restrict__ Wpy,
    const float* __restrict__ glb, const float* __restrict__ ave,
    float* __restrict__ deglb_g, float* __restrict__ fa_g, float* __restrict__ cx,
    float* __restrict__ czc, float* __restrict__ vz, float* __restrict__ szc,
    float* __restrict__ M1){
  const int bx = blockIdx.x, tid = threadIdx.x;
  if(bx >= 64){
    // k0b: M1[jc,i] = sum_k Wc[256+k, 128+jc]*Wpy[k,i]; 2 rows per block
    const int jc = (bx-64)*2 + (tid>>7);
    const int i = tid&127;
    float acc = 0.f;
    for(int k=0;k<F;k++) acc += Wc[(size_t)(256+k)*256 + 128 + jc]*Wpy[(size_t)k*F+i];
    M1[jc*F+i] = acc;
    return;
  }
  const int b = bx;
  __shared__ float glb_s[512], ave_s[512];
  __shared__ float deglb_s[F], cvec_s[3*F], cpy_s[F];
  for(int i=tid;i<512;i+=256){ glb_s[i]=glb[b*512+i]; ave_s[i]=ave[b*512+i]; }
  __syncthreads();
  {
    const int j = tid&127;
    const float* src = (tid<128)? glb_s : ave_s;
    float a0=0.f,a1=0.f,a2=0.f,a3=0.f;
    for(int k=0;k<512;k+=4){
      a0 += WgT[(size_t)(k+0)*128+j]*src[k+0];
      a1 += WgT[(size_t)(k+1)*128+j]*src[k+1];
      a2 += WgT[(size_t)(k+2)*128+j]*src[k+2];
      a3 += WgT[(size_t)(k+3)*128+j]*src[k+3];
    }
    float d = (a0+a1)+(a2+a3) + bg[j];
    if(tid<128){ deglb_s[j]=d; deglb_g[b*F+j]=d; }
    else fa_g[b*F+j]=d;
  }
  __syncthreads();
  for(int i=tid;i<3*F;i+=256){
    float a0=0.f,a1=0.f,a2=0.f,a3=0.f;
    for(int k=0;k<F;k+=4){
      a0 += WcT[(size_t)(k+0)*384+i]*deglb_s[k+0];
      a1 += WcT[(size_t)(k+1)*384+i]*deglb_s[k+1];
      a2 += WcT[(size_t)(k+2)*384+i]*deglb_s[k+2];
      a3 += WcT[(size_t)(k+3)*384+i]*deglb_s[k+3];
    }
    float v = (a0+a1)+(a2+a3) + bc[i];
    cvec_s[i]=v;
    if(i<F) cx[b*F+i]=v;
  }
  __syncthreads();
  if(tid<128){
    const int j = tid;
    float a0=0.f,a1=0.f,a2=0.f,a3=0.f;
    for(int k=0;k<F;k+=4){
      a0 += WpT[(size_t)(k+0)*128+j]*cvec_s[128+k+0];
      a1 += WpT[(size_t)(k+1)*128+j]*cvec_s[128+k+1];
      a2 += WpT[(size_t)(k+2)*128+j]*cvec_s[128+k+2];
      a3 += WpT[(size_t)(k+3)*128+j]*cvec_s[128+k+3];
    }
    cpy_s[j] = (a0+a1)+(a2+a3) + bp[j];
  } else {
    const int j = tid-128;
    float a0=0.f,a1=0.f,a2=0.f,a3=0.f;
    for(int k=0;k<F;k+=4){
      a0 += Wpy[(size_t)(k+0)*128+j]*cvec_s[256+k+0];
      a1 += Wpy[(size_t)(k+1)*128+j]*cvec_s[256+k+1];
      a2 += Wpy[(size_t)(k+2)*128+j]*cvec_s[256+k+2];
      a3 += Wpy[(size_t)(k+3)*128+j]*cvec_s[256+k+3];
    }
    vz[b*F+j] = (a0+a1)+(a2+a3);
  }
  __syncthreads();
  if(tid<128){
    const int j = tid;
    float a0=0.f,a1=0.f,a2=0.f,a3=0.f;
    for(int k=0;k<F;k+=4){
      a0 += Wc[(size_t)(256+k+0)*256 + 128 + j]*cpy_s[k+0];
      a1 += Wc[(size_t)(256+k+1)*256 + 128 + j]*cpy_s[k+1];
      a2 += Wc[(size_t)(256+k+2)*256 + 128 + j]*cpy_s[k+2];
      a3 += Wc[(size_t)(256+k+3)*256 + 128 + j]*cpy_s[k+3];
    }
    czc[b*F+j] = (a0+a1)+(a2+a3);
  } else if(tid<192){
    const int lane = tid-128;
    float p = cpy_s[lane]*cvec_s[256+lane] + cpy_s[64+lane]*cvec_s[256+64+lane];
    p = wsum(p);
    if(lane==0) szc[b]=p;
  }
}

// K2c: per (agent a, batch b): af (WaT, thread-per-j), afx, sx
__global__ __launch_bounds__(256) void k2c_agents(
    const float* __restrict__ nf, const float* __restrict__ WaT, const float* __restrict__ ba,
    const float* __restrict__ Wc,
    const float* __restrict__ deglb_g, const float* __restrict__ fa_g, const float* __restrict__ cx,
    float* __restrict__ afx, float* __restrict__ sx){
  const int a = blockIdx.x, b = blockIdx.y, tid = threadIdx.x;
  __shared__ float src_s[384];   // [deglb | a_start_a | a_end_a]
  __shared__ float af_s[F], cx_s[F];
  if(tid<128){ src_s[tid] = deglb_g[b*F+tid]; cx_s[tid]=cx[b*F+tid]; }
  else if(a<16){
    const int j = tid-128;
    src_s[128+j] = nf[(size_t)(b*F+j)*NTOT + CN + a];
    src_s[256+j] = nf[(size_t)(b*F+j)*NTOT + CN + AN + a];
  }
  __syncthreads();
  if(a<16){
    if(tid<128){
      const int j = tid;
      float a0=0.f,a1=0.f,a2=0.f,a3=0.f;
      for(int k=0;k<384;k+=4){
        a0 += WaT[(size_t)(k+0)*128+j]*src_s[k+0];
        a1 += WaT[(size_t)(k+1)*128+j]*src_s[k+1];
        a2 += WaT[(size_t)(k+2)*128+j]*src_s[k+2];
        a3 += WaT[(size_t)(k+3)*128+j]*src_s[k+3];
      }
      af_s[j] = (a0+a1)+(a2+a3) + ba[j];
    }
  } else if(tid<128){
    af_s[tid] = fa_g[b*F+tid];
  }
  __syncthreads();
  if(tid<128){
    const int j = tid;
    float a0=0.f,a1=0.f,a2=0.f,a3=0.f;
    for(int i=0;i<F;i+=4){
      a0 += af_s[i+0]*Wc[(size_t)(i+0)*256 + 128 + j];
      a1 += af_s[i+1]*Wc[(size_t)(i+1)*256 + 128 + j];
      a2 += af_s[i+2]*Wc[(size_t)(i+2)*256 + 128 + j];
      a3 += af_s[i+3]*Wc[(size_t)(i+3)*256 + 128 + j];
    }
    afx[((size_t)b*NA+a)*F + j] = (a0+a1)+(a2+a3);
  } else if(tid<192){
    const int lane = tid-128;
    float p = af_s[lane]*cx_s[lane] + af_s[64+lane]*cx_s[64+lane];
    p = wsum(p);
    if(lane==0) sx[b*NA+a]=p;
  }
}

// K35: fused scores + chunk softmax + t-accum. Chunk=128 cities, split-K halves.
// Phase-4 staging via global_load_lds (linear LDS dest, inverse-swizzled source).
__global__ __launch_bounds__(256) void k35_flash(const float* __restrict__ nf,
      const float* __restrict__ afx, const float* __restrict__ sx,
      float* __restrict__ pmax, float* __restrict__ psum, float* __restrict__ tpart){
  const int b = blockIdx.y, tid = threadIdx.x;
  const int chunk = blockIdx.x, c0 = chunk*CHK;
  __shared__ float afx_s[NA*F];
  __shared__ float sx_s[NA];
  __shared__ float at_s[NA*CHK];   // partial scores, then exp scores
  __shared__ float4 nf4_s[F*8];    // swizzled 32-city subtile
  __shared__ float red_s[2][NA];
  __shared__ float m_s[NA];
  for(int o=tid;o<NA*F;o+=256) afx_s[o]=afx[(size_t)b*NA*F+o];
  if(tid<NA) sx_s[tid]=sx[b*NA+tid];
  __syncthreads();
  const int h = tid>>7, cl = tid&127, i0 = h*64;
  // phase 1: half-K score partials for city c0+cl (float4 afx broadcast reads)
  float acc[NA];
  #pragma unroll
  for(int a=0;a<NA;a++) acc[a]=0.f;
  {
    const float* base = nf + (size_t)b*F*NTOT + (size_t)i0*NTOT + c0 + cl;
    for(int q=0;q<16;q++){
      float v0 = base[(size_t)(q*4+0)*NTOT];
      float v1 = base[(size_t)(q*4+1)*NTOT];
      float v2 = base[(size_t)(q*4+2)*NTOT];
      float v3 = base[(size_t)(q*4+3)*NTOT];
      #pragma unroll
      for(int a=0;a<NA;a++){
        float4 w = *(const float4*)&afx_s[a*F + i0 + q*4];
        acc[a] += w.x*v0 + w.y*v1 + w.z*v2 + w.w*v3;
      }
    }
  }
  if(h==0){
    #pragma unroll
    for(int a=0;a<NA;a++) at_s[a*CHK+cl] = acc[a];
  }
  __syncthreads();
  const int lane = tid&63;
  const float scale = 0.088388347648318447f;
  if(h==1){
    const int wq = (tid>>6)&1;
    #pragma unroll
    for(int a=0;a<NA;a++){
      acc[a] = (acc[a] + at_s[a*CHK+cl] + sx_s[a])*scale;
      float m = wmax(acc[a]);
      if(lane==0) red_s[wq][a]=m;
    }
  }
  __syncthreads();
  if(tid<NA){
    float m = fmaxf(red_s[0][tid], red_s[1][tid]);
    m_s[tid]=m;
    pmax[(b*NA+tid)*NCHK + chunk]=m;
  }
  __syncthreads();
  if(h==1){
    const int wq = (tid>>6)&1;
    #pragma unroll
    for(int a=0;a<NA;a++){
      float e = __expf(acc[a]-m_s[a]);
      at_s[a*CHK+cl]=e;
      float s = wsum(e);
      if(lane==0) red_s[wq][a]=s;
    }
  }
  __syncthreads();
  if(tid<NA)
    psum[(b*NA+tid)*NCHK + chunk] = red_s[0][tid]+red_s[1][tid];
  // phase 4: tpart over 4 subtiles of 32 cities
  const int i = tid&127, A0 = h*8;
  float ta[9];
  #pragma unroll
  for(int a=0;a<9;a++) ta[a]=0.f;
  for(int s4=0;s4<4;s4++){
    const int csl = s4*32, cs = c0 + csl;
    __syncthreads();
    // linear LDS dest (lane-contiguous per wave) + inverse-swizzled global source:
    // slot ii*8+gp receives column gp^(ii&7), so reads of nf4_s[ii*8+(g^(ii&7))]
    // see nf[ii][g] exactly as before.
    for(int idx=tid; idx<F*8; idx+=256){
      const int ii=idx>>3, gp=idx&7, g=gp^(ii&7);
      __builtin_amdgcn_global_load_lds(
        (const __attribute__((address_space(1))) void*)(nf + (size_t)(b*F+ii)*NTOT + cs + g*4),
        (__attribute__((address_space(3))) void*)&nf4_s[idx], 16, 0, 0);
    }
    __syncthreads();
    #pragma unroll 2
    for(int g=0; g<8; g++){
      float4 v = nf4_s[i*8 + (g^(i&7))];
      #pragma unroll
      for(int a=0;a<9;a++){
        float4 w = *(const float4*)&at_s[(A0+a)*CHK + csl + g*4];
        ta[a] += w.x*v.x + w.y*v.y + w.z*v.z + w.w*v.w;
      }
    }
  }
  float* dst = tpart + (size_t)chunk*64*NA*F + (size_t)b*NA*F;
  #pragma unroll
  for(int a=0;a<9;a++){
    if(h==0 || a>0) dst[(A0+a)*F + i] = ta[a];
  }
}

// K5c: per (b,a): combine 16 chunks with rescale; tn; afz = M1@tn + czc; sz = tn.vz + szc
__global__ __launch_bounds__(128) void k5c_final(const float* __restrict__ M1,
      const float* __restrict__ tpart, const float* __restrict__ pmax, const float* __restrict__ psum,
      const float* __restrict__ czc, const float* __restrict__ vz, const float* __restrict__ szc,
      float* __restrict__ afz, float* __restrict__ szv){
  const int a = blockIdx.x, b = blockIdx.y, tid = threadIdx.x;
  __shared__ float tn_s[F];
  const float* pm = pmax + (b*NA+a)*NCHK;
  const float* ps = psum + (b*NA+a)*NCHK;
  float M=-INFINITY;
  #pragma unroll
  for(int k=0;k<NCHK;k++) M = fmaxf(M, pm[k]);
  float w[NCHK]; float rs=0.f;
  #pragma unroll
  for(int k=0;k<NCHK;k++){ w[k]=__expf(pm[k]-M); rs += ps[k]*w[k]; }
  float s = 0.f;
  #pragma unroll
  for(int k=0;k<NCHK;k++) s += tpart[(size_t)k*64*NA*F + ((size_t)b*NA+a)*F + tid]*w[k];
  tn_s[tid] = s / rs;
  __syncthreads();
  float acc = 0.f;
  const float* m = M1 + (size_t)tid*F;
  for(int i=0;i<F;i++) acc += m[i]*tn_s[i];
  afz[((size_t)b*NA+a)*F + tid] = acc + czc[b*F+tid];
  float p = tn_s[tid]*vz[b*F+tid];
  p = wsum(p);
  __shared__ float red[2];
  if((tid&63)==0) red[tid>>6]=p;
  __syncthreads();
  if(tid==0) szv[b*NA+a] = red[0]+red[1] + szc[b];
}

// K6: logits + tanh + agent softmax. Chunk=128 cities, split-K halves, float4 afz reads.
__global__ __launch_bounds__(256) void k6_out(const float* __restrict__ nf, const float* __restrict__ afz,
      const float* __restrict__ szv, const int* __restrict__ step, float* __restrict__ out){
  const int b = blockIdx.y, tid = threadIdx.x;
  const int chunk = blockIdx.x, c0 = chunk*CHK;
  __shared__ float afz_s[NA*F]; __shared__ float sz_s[NA];
  __shared__ float sc_s[NA*CHK];
  for(int o=tid;o<NA*F;o+=256) afz_s[o]=afz[(size_t)b*NA*F+o];
  if(tid<NA) sz_s[tid]=szv[b*NA+tid];
  __syncthreads();
  const int h = tid>>7, cl = tid&127, i0 = h*64;
  float acc[NA];
  #pragma unroll
  for(int a=0;a<NA;a++) acc[a]=0.f;
  {
    const float* base = nf + (size_t)b*F*NTOT + (size_t)i0*NTOT + c0 + cl;
    for(int q=0;q<16;q++){
      float v0 = base[(size_t)(q*4+0)*NTOT];
      float v1 = base[(size_t)(q*4+1)*NTOT];
      float v2 = base[(size_t)(q*4+2)*NTOT];
      float v3 = base[(size_t)(q*4+3)*NTOT];
      #pragma unroll
      for(int a=0;a<NA;a++){
        float4 w = *(const float4*)&afz_s[a*F + i0 + q*4];
        acc[a] += w.x*v0 + w.y*v1 + w.z*v2 + w.w*v3;
      }
    }
  }
  if(h==0){
    #pragma unroll
    for(int a=0;a<NA;a++) sc_s[a*CHK+cl] = acc[a];
  }
  __syncthreads();
  if(h==1){
    const int A = (step[0] > 0) ? NA : AN;
    const float scale = 0.088388347648318447f;
    float l[NA];
    #pragma unroll
    for(int a=0;a<NA;a++)
      l[a] = tanhf((acc[a] + sc_s[a*CHK+cl] + sz_s[a])*scale)*10.f;
    const bool f17 = (A==NA);
    float m = l[0];
    #pragma unroll
    for(int a=1;a<AN;a++) m = fmaxf(m,l[a]);
    if(f17) m = fmaxf(m,l[16]);
    float ssum=0.f;
    #pragma unroll
    for(int a=0;a<AN;a++){ float e=__expf(l[a]-m); l[a]=e; ssum+=e; }
    float e16=__expf(l[16]-m);
    if(f17){ ssum+=e16; }
    const float inv = 1.f/ssum;
    float* op = out + (size_t)(b*CN + c0 + cl)*A;
    #pragma unroll
    for(int a=0;a<AN;a++) op[a]=l[a]*inv;
    if(f17) op[16]=e16*inv;
  }
}

extern "C" void kernel_launch(void* const* d_in, const int* in_sizes, int n_in,
                              void* d_out, int out_size, void* d_ws, size_t ws_size,
                              hipStream_t stream){
  const float* nf = (const float*)d_in[0];
  const float* Wg = (const float*)d_in[1];
  const float* bg = (const float*)d_in[2];
  const float* Wc = (const float*)d_in[3];
  const float* bc = (const float*)d_in[4];
  const float* Wa = (const float*)d_in[5];
  const float* ba = (const float*)d_in[6];
  const float* Wp = (const float*)d_in[7];
  const float* bp = (const float*)d_in[8];
  const int*  step = (const int*)d_in[9];
  float* out = (float*)d_out;

  float* ws = (float*)d_ws;
  float* glb     = ws;                    // 64*512
  float* ave     = glb + 64*512;          // 64*512
  float* afx     = ave + 64*512;          // 64*17*128
  float* sx      = afx + 64*NA*F;         // 64*17
  float* Wpy     = sx + 64*NA;            // 128*128
  float* M1      = Wpy + F*F;             // 128*128
  float* czc     = M1 + F*F;              // 64*128
  float* vz      = czc + 64*F;            // 64*128
  float* szc     = vz + 64*F;             // 64
  float* pmax    = szc + 64;              // 64*17*16
  float* psum    = pmax + 64*NA*NCHK;     // 64*17*16
  float* deglb_g = psum + 64*NA*NCHK;     // 64*128
  float* fa_g    = deglb_g + 64*F;        // 64*128
  float* cx      = fa_g + 64*F;           // 64*128
  float* WgT     = cx + 64*F;             // 512*128
  float* WcT     = WgT + 512*F;           // 256*384
  float* WpT     = WcT + 256*384;         // 128*128
  float* WaT     = WpT + F*F;             // 384*128
  float* tpart   = WaT + 384*F;           // 16*64*17*128
  float* afz     = tpart + (size_t)NCHK*64*NA*F;  // 64*17*128
  float* szv     = afz + 64*NA*F;         // 64*17

  // L1: fused transposes + Wpy + k1 reductions (independent blocks)
  k_pre1<<<2880,256,0,stream>>>(nf, Wg,Wc,Wp,Wa, WgT,WcT,WpT,WaT, Wpy, glb,ave);
  // L2: fused per-batch prep + M1
  k_pre2<<<128,256,0,stream>>>(WgT,bg, WcT,Wc,bc, WpT,bp, Wpy, glb,ave,
                               deglb_g,fa_g,cx, czc,vz,szc, M1);
  k2c_agents<<<dim3(NA,64),256,0,stream>>>(nf, WaT,ba,Wc, deglb_g,fa_g,cx, afx,sx);
  k35_flash<<<dim3(NCHK,64),256,0,stream>>>(nf, afx, sx, pmax, psum, tpart);
  k5c_final<<<dim3(NA,64),128,0,stream>>>(M1, tpart, pmax, psum, czc, vz, szc, afz, szv);
  k6_out<<<dim3(NCHK,64),256,0,stream>>>(nf, afz, szv, step, out);
}

// Round 14
// 134.677 us; speedup vs baseline: 1.3437x; 1.0137x over previous
//
#include <hip/hip_runtime.h>
#include <math.h>
#include <stdint.h>

#define F 128
#define NTOT 2080
#define CN 2048
#define AN 16
#define NA 17   // max agents (step>0)
#define CHK 128 // cities per chunk (k35/k6)
#define NCHK 16 // CN/CHK

__device__ __forceinline__ float wmax(float v){
  #pragma unroll
  for(int m=32;m;m>>=1) v = fmaxf(v, __shfl_xor(v, m, 64));
  return v;
}
__device__ __forceinline__ float wsum(float v){
  #pragma unroll
  for(int m=32;m;m>>=1) v += __shfl_xor(v, m, 64);
  return v;
}

// K_pre1: fused {k0t transposes | k0a Wpy | k1 reductions} — independent blocks.
__global__ __launch_bounds__(256) void k_pre1(
      const float* __restrict__ nf,
      const float* __restrict__ Wg, const float* __restrict__ Wc,
      const float* __restrict__ Wp, const float* __restrict__ Wa,
      float* __restrict__ WgT, float* __restrict__ WcT,
      float* __restrict__ WpT, float* __restrict__ WaT,
      float* __restrict__ Wpy,
      float* __restrict__ glb, float* __restrict__ ave){
  __shared__ float tile[32][33];
  const int bx = blockIdx.x, tid = threadIdx.x;
  if(bx < 768){
    const int z = bx/192, rem = bx%192;
    const int c0 = (rem&15)*32, r0 = (rem>>4)*32;
    const float* src; float* dst; int R, C;
    if(z==0){ src=Wg; dst=WgT; R=128; C=512; }
    else if(z==1){ src=Wc; dst=WcT; R=384; C=256; }
    else if(z==2){ src=Wp; dst=WpT; R=128; C=128; }
    else { src=Wa; dst=WaT; R=128; C=384; }
    if(c0>=C || r0>=R) return;
    const int tx = tid&31, ty = tid>>5;   // 32x8
    #pragma unroll
    for(int rr=0;rr<4;rr++)
      tile[ty+rr*8][tx] = src[(size_t)(r0+ty+rr*8)*C + c0 + tx];
    __syncthreads();
    #pragma unroll
    for(int rr=0;rr<4;rr++)
      dst[(size_t)(c0+ty+rr*8)*R + r0 + tx] = tile[tx][ty+rr*8];
    return;
  }
  if(bx < 832){
    const int k = (bx-768)*2 + (tid>>7);
    const int i = tid&127;
    float acc = 0.f;
    const float* wp = Wp + (size_t)k*F;
    for(int j=0;j<F;j++) acc += wp[j]*Wc[(size_t)(128+j)*256 + 128 + i];
    Wpy[k*F+i] = acc;
    return;
  }
  {
    const int r = bx-832;
    const int jg = r&31, b = r>>5;
    const int w = tid>>6, lane = tid&63;
    const int j = jg*4 + w;
    const float4* row = (const float4*)(nf + (size_t)(b*F + j)*NTOT);
    float cmax=-INFINITY, csum=0.f, smax=-INFINITY, ssum=0.f, emax=-INFINITY, esum=0.f;
    for(int n4 = lane; n4 < 520; n4 += 64){
      float4 v = row[n4];
      float mx = fmaxf(fmaxf(v.x,v.y), fmaxf(v.z,v.w));
      float sm = (v.x+v.y)+(v.z+v.w);
      if(n4 < 512){ cmax=fmaxf(cmax,mx); csum+=sm; }
      else if(n4 < 516){ smax=fmaxf(smax,mx); ssum+=sm; }
      else { emax=fmaxf(emax,mx); esum+=sm; }
    }
    cmax=wmax(cmax); csum=wsum(csum); smax=wmax(smax); ssum=wsum(ssum); emax=wmax(emax); esum=wsum(esum);
    if(lane==0){
      const int gb = b*4*F;
      glb[gb + j]       = fmaxf(cmax, fmaxf(smax,emax));
      glb[gb + F + j]   = cmax;
      glb[gb + 2*F + j] = smax;
      glb[gb + 3*F + j] = emax;
      float tS = csum+ssum+esum;
      ave[gb + j]       = tS / 2080.f;
      ave[gb + F + j]   = csum / 2048.f;
      ave[gb + 2*F + j] = ssum / 16.f;
      ave[gb + 3*F + j] = esum / 16.f;
    }
  }
}

// K_pre2: fused {k2a per-batch prep (blocks 0..63) | k0b M1 rows (blocks 64..127)}
__global__ __launch_bounds__(256) void k_pre2(
    const float* __restrict__ WgT, const float* __restrict__ bg,
    const float* __restrict__ WcT, const float* __restrict__ Wc, const float* __restrict__ bc,
    const float* __restrict__ WpT, const float* __restrict__ bp,
    const float* __restrict__ Wpy,
    const float* __restrict__ glb, const float* __restrict__ ave,
    float* __restrict__ deglb_g, float* __restrict__ fa_g, float* __restrict__ cx,
    float* __restrict__ czc, float* __restrict__ vz, float* __restrict__ szc,
    float* __restrict__ M1){
  const int bx = blockIdx.x, tid = threadIdx.x;
  if(bx >= 64){
    const int jc = (bx-64)*2 + (tid>>7);
    const int i = tid&127;
    float acc = 0.f;
    for(int k=0;k<F;k++) acc += Wc[(size_t)(256+k)*256 + 128 + jc]*Wpy[(size_t)k*F+i];
    M1[jc*F+i] = acc;
    return;
  }
  const int b = bx;
  __shared__ float glb_s[512], ave_s[512];
  __shared__ float deglb_s[F], cvec_s[3*F], cpy_s[F];
  for(int i=tid;i<512;i+=256){ glb_s[i]=glb[b*512+i]; ave_s[i]=ave[b*512+i]; }
  __syncthreads();
  {
    const int j = tid&127;
    const float* src = (tid<128)? glb_s : ave_s;
    float a0=0.f,a1=0.f,a2=0.f,a3=0.f;
    for(int k=0;k<512;k+=4){
      a0 += WgT[(size_t)(k+0)*128+j]*src[k+0];
      a1 += WgT[(size_t)(k+1)*128+j]*src[k+1];
      a2 += WgT[(size_t)(k+2)*128+j]*src[k+2];
      a3 += WgT[(size_t)(k+3)*128+j]*src[k+3];
    }
    float d = (a0+a1)+(a2+a3) + bg[j];
    if(tid<128){ deglb_s[j]=d; deglb_g[b*F+j]=d; }
    else fa_g[b*F+j]=d;
  }
  __syncthreads();
  for(int i=tid;i<3*F;i+=256){
    float a0=0.f,a1=0.f,a2=0.f,a3=0.f;
    for(int k=0;k<F;k+=4){
      a0 += WcT[(size_t)(k+0)*384+i]*deglb_s[k+0];
      a1 += WcT[(size_t)(k+1)*384+i]*deglb_s[k+1];
      a2 += WcT[(size_t)(k+2)*384+i]*deglb_s[k+2];
      a3 += WcT[(size_t)(k+3)*384+i]*deglb_s[k+3];
    }
    float v = (a0+a1)+(a2+a3) + bc[i];
    cvec_s[i]=v;
    if(i<F) cx[b*F+i]=v;
  }
  __syncthreads();
  if(tid<128){
    const int j = tid;
    float a0=0.f,a1=0.f,a2=0.f,a3=0.f;
    for(int k=0;k<F;k+=4){
      a0 += WpT[(size_t)(k+0)*128+j]*cvec_s[128+k+0];
      a1 += WpT[(size_t)(k+1)*128+j]*cvec_s[128+k+1];
      a2 += WpT[(size_t)(k+2)*128+j]*cvec_s[128+k+2];
      a3 += WpT[(size_t)(k+3)*128+j]*cvec_s[128+k+3];
    }
    cpy_s[j] = (a0+a1)+(a2+a3) + bp[j];
  } else {
    const int j = tid-128;
    float a0=0.f,a1=0.f,a2=0.f,a3=0.f;
    for(int k=0;k<F;k+=4){
      a0 += Wpy[(size_t)(k+0)*128+j]*cvec_s[256+k+0];
      a1 += Wpy[(size_t)(k+1)*128+j]*cvec_s[256+k+1];
      a2 += Wpy[(size_t)(k+2)*128+j]*cvec_s[256+k+2];
      a3 += Wpy[(size_t)(k+3)*128+j]*cvec_s[256+k+3];
    }
    vz[b*F+j] = (a0+a1)+(a2+a3);
  }
  __syncthreads();
  if(tid<128){
    const int j = tid;
    float a0=0.f,a1=0.f,a2=0.f,a3=0.f;
    for(int k=0;k<F;k+=4){
      a0 += Wc[(size_t)(256+k+0)*256 + 128 + j]*cpy_s[k+0];
      a1 += Wc[(size_t)(256+k+1)*256 + 128 + j]*cpy_s[k+1];
      a2 += Wc[(size_t)(256+k+2)*256 + 128 + j]*cpy_s[k+2];
      a3 += Wc[(size_t)(256+k+3)*256 + 128 + j]*cpy_s[k+3];
    }
    czc[b*F+j] = (a0+a1)+(a2+a3);
  } else if(tid<192){
    const int lane = tid-128;
    float p = cpy_s[lane]*cvec_s[256+lane] + cpy_s[64+lane]*cvec_s[256+64+lane];
    p = wsum(p);
    if(lane==0) szc[b]=p;
  }
}

// K2c: per (agent a, batch b): af (WaT, thread-per-j), afx, sx
__global__ __launch_bounds__(256) void k2c_agents(
    const float* __restrict__ nf, const float* __restrict__ WaT, const float* __restrict__ ba,
    const float* __restrict__ Wc,
    const float* __restrict__ deglb_g, const float* __restrict__ fa_g, const float* __restrict__ cx,
    float* __restrict__ afx, float* __restrict__ sx){
  const int a = blockIdx.x, b = blockIdx.y, tid = threadIdx.x;
  __shared__ float src_s[384];
  __shared__ float af_s[F], cx_s[F];
  if(tid<128){ src_s[tid] = deglb_g[b*F+tid]; cx_s[tid]=cx[b*F+tid]; }
  else if(a<16){
    const int j = tid-128;
    src_s[128+j] = nf[(size_t)(b*F+j)*NTOT + CN + a];
    src_s[256+j] = nf[(size_t)(b*F+j)*NTOT + CN + AN + a];
  }
  __syncthreads();
  if(a<16){
    if(tid<128){
      const int j = tid;
      float a0=0.f,a1=0.f,a2=0.f,a3=0.f;
      for(int k=0;k<384;k+=4){
        a0 += WaT[(size_t)(k+0)*128+j]*src_s[k+0];
        a1 += WaT[(size_t)(k+1)*128+j]*src_s[k+1];
        a2 += WaT[(size_t)(k+2)*128+j]*src_s[k+2];
        a3 += WaT[(size_t)(k+3)*128+j]*src_s[k+3];
      }
      af_s[j] = (a0+a1)+(a2+a3) + ba[j];
    }
  } else if(tid<128){
    af_s[tid] = fa_g[b*F+tid];
  }
  __syncthreads();
  if(tid<128){
    const int j = tid;
    float a0=0.f,a1=0.f,a2=0.f,a3=0.f;
    for(int i=0;i<F;i+=4){
      a0 += af_s[i+0]*Wc[(size_t)(i+0)*256 + 128 + j];
      a1 += af_s[i+1]*Wc[(size_t)(i+1)*256 + 128 + j];
      a2 += af_s[i+2]*Wc[(size_t)(i+2)*256 + 128 + j];
      a3 += af_s[i+3]*Wc[(size_t)(i+3)*256 + 128 + j];
    }
    afx[((size_t)b*NA+a)*F + j] = (a0+a1)+(a2+a3);
  } else if(tid<192){
    const int lane = tid-128;
    float p = af_s[lane]*cx_s[lane] + af_s[64+lane]*cx_s[64+lane];
    p = wsum(p);
    if(lane==0) sx[b*NA+a]=p;
  }
}

// K35: fused scores + chunk softmax + t-accum. Chunk=128 cities, split-K halves.
// Phase-4 staging via global_load_lds (linear LDS dest, inverse-swizzled source).
__global__ __launch_bounds__(256) void k35_flash(const float* __restrict__ nf,
      const float* __restrict__ afx, const float* __restrict__ sx,
      float* __restrict__ pmax, float* __restrict__ psum, float* __restrict__ tpart){
  const int b = blockIdx.y, tid = threadIdx.x;
  const int chunk = blockIdx.x, c0 = chunk*CHK;
  __shared__ float afx_s[NA*F];
  __shared__ float sx_s[NA];
  __shared__ float at_s[NA*CHK];   // partial scores, then exp scores
  __shared__ float4 nf4_s[F*8];    // swizzled 32-city subtile
  __shared__ float red_s[2][NA];
  __shared__ float m_s[NA];
  for(int o=tid;o<NA*F;o+=256) afx_s[o]=afx[(size_t)b*NA*F+o];
  if(tid<NA) sx_s[tid]=sx[b*NA+tid];
  __syncthreads();
  const int h = tid>>7, cl = tid&127, i0 = h*64;
  float acc[NA];
  #pragma unroll
  for(int a=0;a<NA;a++) acc[a]=0.f;
  {
    const float* base = nf + (size_t)b*F*NTOT + (size_t)i0*NTOT + c0 + cl;
    for(int q=0;q<16;q++){
      float v0 = base[(size_t)(q*4+0)*NTOT];
      float v1 = base[(size_t)(q*4+1)*NTOT];
      float v2 = base[(size_t)(q*4+2)*NTOT];
      float v3 = base[(size_t)(q*4+3)*NTOT];
      #pragma unroll
      for(int a=0;a<NA;a++){
        float4 w = *(const float4*)&afx_s[a*F + i0 + q*4];
        acc[a] += w.x*v0 + w.y*v1 + w.z*v2 + w.w*v3;
      }
    }
  }
  if(h==0){
    #pragma unroll
    for(int a=0;a<NA;a++) at_s[a*CHK+cl] = acc[a];
  }
  __syncthreads();
  const int lane = tid&63;
  const float scale = 0.088388347648318447f;
  if(h==1){
    const int wq = (tid>>6)&1;
    #pragma unroll
    for(int a=0;a<NA;a++){
      acc[a] = (acc[a] + at_s[a*CHK+cl] + sx_s[a])*scale;
      float m = wmax(acc[a]);
      if(lane==0) red_s[wq][a]=m;
    }
  }
  __syncthreads();
  if(tid<NA){
    float m = fmaxf(red_s[0][tid], red_s[1][tid]);
    m_s[tid]=m;
    pmax[(b*NA+tid)*NCHK + chunk]=m;
  }
  __syncthreads();
  if(h==1){
    const int wq = (tid>>6)&1;
    #pragma unroll
    for(int a=0;a<NA;a++){
      float e = __expf(acc[a]-m_s[a]);
      at_s[a*CHK+cl]=e;
      float s = wsum(e);
      if(lane==0) red_s[wq][a]=s;
    }
  }
  __syncthreads();
  if(tid<NA)
    psum[(b*NA+tid)*NCHK + chunk] = red_s[0][tid]+red_s[1][tid];
  const int i = tid&127, A0 = h*8;
  float ta[9];
  #pragma unroll
  for(int a=0;a<9;a++) ta[a]=0.f;
  for(int s4=0;s4<4;s4++){
    const int csl = s4*32, cs = c0 + csl;
    __syncthreads();
    for(int idx=tid; idx<F*8; idx+=256){
      const int ii=idx>>3, gp=idx&7, g=gp^(ii&7);
      __builtin_amdgcn_global_load_lds(
        (const __attribute__((address_space(1))) void*)(nf + (size_t)(b*F+ii)*NTOT + cs + g*4),
        (__attribute__((address_space(3))) void*)&nf4_s[idx], 16, 0, 0);
    }
    __syncthreads();
    #pragma unroll 2
    for(int g=0; g<8; g++){
      float4 v = nf4_s[i*8 + (g^(i&7))];
      #pragma unroll
      for(int a=0;a<9;a++){
        float4 w = *(const float4*)&at_s[(A0+a)*CHK + csl + g*4];
        ta[a] += w.x*v.x + w.y*v.y + w.z*v.z + w.w*v.w;
      }
    }
  }
  float* dst = tpart + (size_t)chunk*64*NA*F + (size_t)b*NA*F;
  #pragma unroll
  for(int a=0;a<9;a++){
    if(h==0 || a>0) dst[(A0+a)*F + i] = ta[a];
  }
}

// K5c: per (b,a): combine 16 chunks with rescale; tn; afz = M1@tn + czc; sz = tn.vz + szc
__global__ __launch_bounds__(128) void k5c_final(const float* __restrict__ M1,
      const float* __restrict__ tpart, const float* __restrict__ pmax, const float* __restrict__ psum,
      const float* __restrict__ czc, const float* __restrict__ vz, const float* __restrict__ szc,
      float* __restrict__ afz, float* __restrict__ szv){
  const int a = blockIdx.x, b = blockIdx.y, tid = threadIdx.x;
  __shared__ float tn_s[F];
  const float* pm = pmax + (b*NA+a)*NCHK;
  const float* ps = psum + (b*NA+a)*NCHK;
  float M=-INFINITY;
  #pragma unroll
  for(int k=0;k<NCHK;k++) M = fmaxf(M, pm[k]);
  float w[NCHK]; float rs=0.f;
  #pragma unroll
  for(int k=0;k<NCHK;k++){ w[k]=__expf(pm[k]-M); rs += ps[k]*w[k]; }
  float s = 0.f;
  #pragma unroll
  for(int k=0;k<NCHK;k++) s += tpart[(size_t)k*64*NA*F + ((size_t)b*NA+a)*F + tid]*w[k];
  tn_s[tid] = s / rs;
  __syncthreads();
  float acc = 0.f;
  const float* m = M1 + (size_t)tid*F;
  for(int i=0;i<F;i++) acc += m[i]*tn_s[i];
  afz[((size_t)b*NA+a)*F + tid] = acc + czc[b*F+tid];
  float p = tn_s[tid]*vz[b*F+tid];
  p = wsum(p);
  __shared__ float red[2];
  if((tid&63)==0) red[tid>>6]=p;
  __syncthreads();
  if(tid==0) szv[b*NA+a] = red[0]+red[1] + szc[b];
}

// K6: logits + tanh + agent softmax. Phase-1 frozen (R6 structure).
// Epilogue: both thread-halves active (agent-split) + coalesced float4 output staging.
__global__ __launch_bounds__(256) void k6_out(const float* __restrict__ nf, const float* __restrict__ afz,
      const float* __restrict__ szv, const int* __restrict__ step, float* __restrict__ out){
  const int b = blockIdx.y, tid = threadIdx.x;
  const int chunk = blockIdx.x, c0 = chunk*CHK;
  __shared__ float afz_s[NA*F]; __shared__ float sz_s[NA];
  __shared__ float sc_s[NA*CHK];      // h0 partial scores
  __shared__ float hi_s[8*CHK];       // full scores a=9..16 (from h1)
  __shared__ float pmx_s[2*CHK], psm_s[2*CHK];
  __shared__ float ot_s[NA*CHK];      // output staging, [c][a]
  for(int o=tid;o<NA*F;o+=256) afz_s[o]=afz[(size_t)b*NA*F+o];
  if(tid<NA) sz_s[tid]=szv[b*NA+tid];
  __syncthreads();
  const int h = tid>>7, cl = tid&127, i0 = h*64;
  float acc[NA];
  #pragma unroll
  for(int a=0;a<NA;a++) acc[a]=0.f;
  {
    const float* base = nf + (size_t)b*F*NTOT + (size_t)i0*NTOT + c0 + cl;
    for(int q=0;q<16;q++){
      float v0 = base[(size_t)(q*4+0)*NTOT];
      float v1 = base[(size_t)(q*4+1)*NTOT];
      float v2 = base[(size_t)(q*4+2)*NTOT];
      float v3 = base[(size_t)(q*4+3)*NTOT];
      #pragma unroll
      for(int a=0;a<NA;a++){
        float4 w = *(const float4*)&afz_s[a*F + i0 + q*4];
        acc[a] += w.x*v0 + w.y*v1 + w.z*v2 + w.w*v3;
      }
    }
  }
  if(h==0){
    #pragma unroll
    for(int a=0;a<NA;a++) sc_s[a*CHK+cl] = acc[a];
  }
  __syncthreads();
  // h1: full scores for its city; ship a=9..16 to hi_s
  if(h==1){
    #pragma unroll
    for(int a=0;a<NA;a++) acc[a] += sc_s[a*CHK+cl];
    #pragma unroll
    for(int a=9;a<NA;a++) hi_s[(a-9)*CHK+cl] = acc[a];
  }
  __syncthreads();
  // epilogue on ALL 256 threads: city = cl; h1 -> agents 0..8, h0 -> agents 9..16
  const int A = (step[0] > 0) ? NA : AN;
  const float scale = 0.088388347648318447f;
  float l[9];
  int na;
  int aBeg;
  if(h==1){ na = 9; aBeg = 0; }
  else { na = A - 9; aBeg = 9; }
  #pragma unroll
  for(int a2=0;a2<9;a2++){
    if(a2<na){
      float s = (h==1)? acc[aBeg+a2] : hi_s[a2*CHK+cl];
      l[a2] = tanhf((s + sz_s[aBeg+a2])*scale)*10.f;
    }
  }
  float pm = -INFINITY;
  #pragma unroll
  for(int a2=0;a2<9;a2++) if(a2<na) pm = fmaxf(pm, l[a2]);
  pmx_s[h*CHK+cl] = pm;
  __syncthreads();
  const float m = fmaxf(pmx_s[cl], pmx_s[CHK+cl]);
  float es = 0.f;
  #pragma unroll
  for(int a2=0;a2<9;a2++) if(a2<na){ float e = __expf(l[a2]-m); l[a2]=e; es+=e; }
  psm_s[h*CHK+cl] = es;
  __syncthreads();
  const float inv = 1.f/(psm_s[cl]+psm_s[CHK+cl]);
  #pragma unroll
  for(int a2=0;a2<9;a2++) if(a2<na) ot_s[cl*A + aBeg+a2] = l[a2]*inv;
  __syncthreads();
  // coalesced flush: A*CHK floats, 16B-aligned for A=17 and A=16
  float* dstg = out + (size_t)(b*CN + c0)*A;
  const int n4 = (A*CHK)>>2;
  for(int idx=tid; idx<n4; idx+=256)
    ((float4*)dstg)[idx] = ((const float4*)ot_s)[idx];
}

extern "C" void kernel_launch(void* const* d_in, const int* in_sizes, int n_in,
                              void* d_out, int out_size, void* d_ws, size_t ws_size,
                              hipStream_t stream){
  const float* nf = (const float*)d_in[0];
  const float* Wg = (const float*)d_in[1];
  const float* bg = (const float*)d_in[2];
  const float* Wc = (const float*)d_in[3];
  const float* bc = (const float*)d_in[4];
  const float* Wa = (const float*)d_in[5];
  const float* ba = (const float*)d_in[6];
  const float* Wp = (const float*)d_in[7];
  const float* bp = (const float*)d_in[8];
  const int*  step = (const int*)d_in[9];
  float* out = (float*)d_out;

  float* ws = (float*)d_ws;
  float* glb     = ws;                    // 64*512
  float* ave     = glb + 64*512;          // 64*512
  float* afx     = ave + 64*512;          // 64*17*128
  float* sx      = afx + 64*NA*F;         // 64*17
  float* Wpy     = sx + 64*NA;            // 128*128
  float* M1      = Wpy + F*F;             // 128*128
  float* czc     = M1 + F*F;              // 64*128
  float* vz      = czc + 64*F;            // 64*128
  float* szc     = vz + 64*F;             // 64
  float* pmax    = szc + 64;              // 64*17*16
  float* psum    = pmax + 64*NA*NCHK;     // 64*17*16
  float* deglb_g = psum + 64*NA*NCHK;     // 64*128
  float* fa_g    = deglb_g + 64*F;        // 64*128
  float* cx      = fa_g + 64*F;           // 64*128
  float* WgT     = cx + 64*F;             // 512*128
  float* WcT     = WgT + 512*F;           // 256*384
  float* WpT     = WcT + 256*384;         // 128*128
  float* WaT     = WpT + F*F;             // 384*128
  float* tpart   = WaT + 384*F;           // 16*64*17*128
  float* afz     = tpart + (size_t)NCHK*64*NA*F;  // 64*17*128
  float* szv     = afz + 64*NA*F;         // 64*17

  k_pre1<<<2880,256,0,stream>>>(nf, Wg,Wc,Wp,Wa, WgT,WcT,WpT,WaT, Wpy, glb,ave);
  k_pre2<<<128,256,0,stream>>>(WgT,bg, WcT,Wc,bc, WpT,bp, Wpy, glb,ave,
                               deglb_g,fa_g,cx, czc,vz,szc, M1);
  k2c_agents<<<dim3(NA,64),256,0,stream>>>(nf, WaT,ba,Wc, deglb_g,fa_g,cx, afx,sx);
  k35_flash<<<dim3(NCHK,64),256,0,stream>>>(nf, afx, sx, pmax, psum, tpart);
  k5c_final<<<dim3(NA,64),128,0,stream>>>(M1, tpart, pmax, psum, czc, vz, szc, afz, szv);
  k6_out<<<dim3(NCHK,64),256,0,stream>>>(nf, afz, szv, step, out);
}